// Round 8
// baseline (2605.347 us; speedup 1.0000x reference)
//
#include <hip/hip_runtime.h>
#include <math.h>

#define BB 4
#define CC 132
#define TT 32
#define NN 64
#define HIDD 256
#define G4 1024
#define CIN 392
#define KK 16
#define HOFF 136   // CC + OFF: start of h columns in W
#define GRID 256

typedef __attribute__((ext_vector_type(8))) short bf16x8;
typedef __attribute__((ext_vector_type(4))) float f32x4;

__device__ __forceinline__ float fsigm(float x) { return 1.0f / (1.0f + __expf(-x)); }
__device__ __forceinline__ float ftanh(float x) { float e = __expf(2.0f * x); return 1.0f - 2.0f / (e + 1.0f); }
__device__ __forceinline__ unsigned short f2bf(float x) {
    union { float f; unsigned u; } v; v.f = x;
    unsigned r = v.u + 0x7fffu + ((v.u >> 16) & 1u);   // RNE
    return (unsigned short)(r >> 16);
}

// ---------------------------------------------------------------------------
// W -> MFMA fragments, gate-interleaved permutation g' = 4*j + gate.
// grid = 64 (g'-tiles of 16), block = 256.
// ---------------------------------------------------------------------------
__global__ __launch_bounds__(256) void ktrans2(const float* __restrict__ W,
                                               const float* __restrict__ bias,
                                               unsigned short* __restrict__ WXf,
                                               unsigned short* __restrict__ WHf,
                                               unsigned short* __restrict__ WposA,
                                               float* __restrict__ biasP) {
    int gt = blockIdx.x;
    int tid = threadIdx.x;
    __shared__ float Wl[16][CIN];
    for (int row = 0; row < 16; ++row) {
        int orig = (row & 3) * 256 + gt * 4 + (row >> 2);   // gate*256 + j
        for (int c = tid; c < CIN; c += 256)
            Wl[row][c] = W[(size_t)orig * CIN + c];
    }
    __syncthreads();
    for (int f = tid; f < 320; f += 256) {           // WXf: 5 ks x 64 lanes
        int ks = f >> 6, l = f & 63;
        bf16x8 v;
        #pragma unroll
        for (int j = 0; j < 8; ++j) {
            int c = ks * 32 + (l >> 4) * 8 + j;
            float w = (c < CC) ? Wl[l & 15][c] : ((c < HOFF) ? -Wl[l & 15][c] : 0.0f);
            v[j] = (short)f2bf(w);
        }
        *(bf16x8*)&WXf[((size_t)(gt * 5 + ks)) * 512 + l * 8] = v;
    }
    for (int f = tid; f < 512; f += 256) {           // WHf: 8 ks x 64 lanes
        int ks = f >> 6, l = f & 63;
        bf16x8 v;
        #pragma unroll
        for (int j = 0; j < 8; ++j) {
            int c = HOFF + ks * 32 + (l >> 4) * 8 + j;
            v[j] = (short)f2bf(Wl[l & 15][c]);
        }
        *(bf16x8*)&WHf[((size_t)(gt * 8 + ks)) * 512 + l * 8] = v;
    }
    if (tid < 64) {                                  // WposA: 1 ks
        bf16x8 v;
        #pragma unroll
        for (int e = 0; e < 8; ++e) {
            int c = (tid >> 4) * 8 + e;
            v[e] = (c < 4) ? (short)f2bf(Wl[tid & 15][CC + c]) : (short)0;
        }
        *(bf16x8*)&WposA[(size_t)gt * 512 + tid * 8] = v;
    }
    if (tid < 16)
        biasP[gt * 16 + tid] = bias[(tid & 3) * 256 + gt * 4 + (tid >> 2)];
}

// ---------------------------------------------------------------------------
// Fused prep: x -> A-frags; pos -> A-frag k-slice; bit-exact top-k.
// grid = 128 (t,b), block 256.
// ---------------------------------------------------------------------------
__global__ __launch_bounds__(256) void kprep(const float* __restrict__ in,
                                             int* __restrict__ idxw,
                                             float* __restrict__ outI,
                                             unsigned short* __restrict__ xf,
                                             unsigned short* __restrict__ posAf) {
    int t = blockIdx.x >> 2, b = blockIdx.x & 3;
    int tid = threadIdx.x;
    int tprev = t ? t - 1 : 0;

    __shared__ unsigned short X[64][160];
    {
        int n = tid & 63, cg = tid >> 6;
        for (int c = cg; c < 160; c += 4) {
            float v = 0.0f;
            if (c < CC)        v = in[(((size_t)b * CC + c) * TT + t) * NN + n];
            else if (c < HOFF) v = in[(((size_t)b * CC + (c - CC)) * TT + t) * NN + n];
            X[n][c] = f2bf(v);
        }
        __syncthreads();
        for (int i = 0; i < 5; ++i) {
            int f = i * 256 + tid;
            int mtn = f / 320, r = f % 320;
            int ks = r >> 6, l = r & 63;
            uint4 v = *(const uint4*)&X[mtn * 16 + (l & 15)][ks * 32 + (l >> 4) * 8];
            *(uint4*)&xf[(((size_t)(blockIdx.x * 4 + mtn)) * 5 + ks) * 512 + l * 8] = v;
        }
    }
    {
        int mt = tid >> 6, l = tid & 63;
        bf16x8 v;
        #pragma unroll
        for (int e = 0; e < 8; ++e) {
            int c = (l >> 4) * 8 + e;
            float p = (c < 4) ? in[(((size_t)b * CC + c) * TT + tprev) * NN + mt * 16 + (l & 15)] : 0.0f;
            v[e] = (short)f2bf(p);
        }
        *(bf16x8*)&posAf[(((size_t)(t * BB + b)) * 4 + mt) * 512 + l * 8] = v;
    }
    {
        int lane = tid & 63, w = tid >> 6;
        const float* base = in + (size_t)b * CC * TT * NN;
        float p0 = base[(0 * TT + tprev) * NN + lane];
        float p1 = base[(1 * TT + tprev) * NN + lane];
        float p2 = base[(2 * TT + tprev) * NN + lane];
        float q0 = base[(0 * TT + t) * NN + lane];
        float q1 = base[(1 * TT + t) * NN + lane];
        float q2 = base[(2 * TT + t) * NN + lane];
        for (int nn = 0; nn < 16; ++nn) {
            int n = w * 16 + nn;
            float a0 = __shfl(q0, n), a1 = __shfl(q1, n), a2 = __shfl(q2, n);
            float dx = a0 - p0, dy = a1 - p1, dz = a2 - p2;
            float s01 = __fadd_rn(__fmul_rn(dx, dx), __fmul_rn(dy, dy));
            float d = __fadd_rn(s01, __fmul_rn(dz, dz));
            unsigned long long key =
                ((unsigned long long)__float_as_uint(d) << 32) | (unsigned)lane;
            #pragma unroll
            for (int k = 2; k <= 64; k <<= 1) {
                #pragma unroll
                for (int j = k >> 1; j > 0; j >>= 1) {
                    unsigned long long other = __shfl_xor(key, j);
                    bool up = (lane & k) == 0;
                    bool upper = (lane & j) != 0;
                    bool keepMax = up ? upper : !upper;
                    unsigned long long mn = key < other ? key : other;
                    unsigned long long mx = key < other ? other : key;
                    key = keepMax ? mx : mn;
                }
            }
            if (lane < KK) {
                int m = (int)(key & 0xffffffffu);
                idxw[((t * BB + b) * NN + n) * KK + lane] = m;
                outI[((b * TT + t) * NN + n) * KK + lane] = (float)m;
            }
        }
    }
}

// ---------------------------------------------------------------------------
// XA = x*Wx + biasP (MFMA, permuted cols). grid = 512, block = 256 (4 waves).
// ---------------------------------------------------------------------------
__global__ __launch_bounds__(256) void kxa3(const unsigned short* __restrict__ xf,
                                            const unsigned short* __restrict__ WXf,
                                            const float* __restrict__ biasP,
                                            float* __restrict__ XA) {
    int gq = blockIdx.x & 3, tb = blockIdx.x >> 2;
    int w = threadIdx.x >> 6, l = threadIdx.x & 63;
    int gbase = gq * 16 + w * 4;
    f32x4 acc[4][4];
    #pragma unroll
    for (int a = 0; a < 4; ++a)
        #pragma unroll
        for (int g = 0; g < 4; ++g) acc[a][g] = (f32x4){0.f, 0.f, 0.f, 0.f};
    #pragma unroll
    for (int ks = 0; ks < 5; ++ks) {
        bf16x8 af[4], bfr[4];
        #pragma unroll
        for (int m = 0; m < 4; ++m)
            af[m] = *(const bf16x8*)&xf[(((size_t)(tb * 4 + m)) * 5 + ks) * 512 + l * 8];
        #pragma unroll
        for (int g = 0; g < 4; ++g)
            bfr[g] = *(const bf16x8*)&WXf[((size_t)((gbase + g) * 5 + ks)) * 512 + l * 8];
        #pragma unroll
        for (int m = 0; m < 4; ++m)
            #pragma unroll
            for (int g = 0; g < 4; ++g)
                acc[m][g] = __builtin_amdgcn_mfma_f32_16x16x32_bf16(af[m], bfr[g], acc[m][g], 0, 0, 0);
    }
    int rb = tb * 64;
    #pragma unroll
    for (int g = 0; g < 4; ++g) {
        int gcol = (gbase + g) * 16 + (l & 15);
        float bv = biasP[gcol];
        #pragma unroll
        for (int m = 0; m < 4; ++m)
            #pragma unroll
            for (int r = 0; r < 4; ++r) {
                int row = rb + m * 16 + (l >> 4) * 4 + r;
                XA[(size_t)row * G4 + gcol] = acc[m][g][r] + bv;
            }
    }
}

// ---------------------------------------------------------------------------
// Persistent t-loop (cooperative). grid = 256, block = 512.
// Per step: block-local HP-slice GEMM (LDS) + cell; ONE custom grid barrier
// per step (per-step arrival counter + relaxed spin on phase; explicit
// threadfence release/acquire). Replaces 32 dispatches.
// ---------------------------------------------------------------------------
__global__ __launch_bounds__(512) void kloop2(const float* __restrict__ XA,
                                              const unsigned short* __restrict__ WHf,
                                              const unsigned short* __restrict__ WposA,
                                              const unsigned short* __restrict__ posAf,
                                              unsigned short* __restrict__ hb0,
                                              unsigned short* __restrict__ hb1,
                                              const int* __restrict__ idxw,
                                              float* __restrict__ c0,
                                              float* __restrict__ c1,
                                              float* __restrict__ out,
                                              int* __restrict__ bar) {
    int bid = blockIdx.x;
    int b = bid & 3, q = (bid >> 2) & 15, nh = bid >> 6;
    int tid = threadIdx.x;
    __shared__ float LDSG[64][68];          // [m][g'local(64)+pad]
    __shared__ float cmbH[256], cmbC[256];

    // fixed per-thread identities
    int kh = tid >> 8, p = tid & 255;
    int nl = p >> 4, jl = p & 15;
    int n = nh * 16 + nl;
    int jg = q * 16 + jl;
    int wv = tid >> 6, l = tid & 63;
    int mt = wv & 3, gh = wv >> 2;

    for (int t = 0; t < TT; ++t) {
        const unsigned short* hr = (t & 1) ? hb0 : hb1;
        unsigned short* hw       = (t & 1) ? hb1 : hb0;
        const float* cp          = (t & 1) ? c0 : c1;
        float* cn                = (t & 1) ? c1 : c0;

        // earliest loads: indices + XA quad (constant inputs, no hazard)
        const int* irow = &idxw[((size_t)(t * BB + b) * NN + n) * KK + kh * 8];
        int4 mi0 = *(const int4*)irow;
        int4 mi1 = *(const int4*)(irow + 4);
        const float4 xav = *(const float4*)&XA[((size_t)(t * BB + b) * NN + n) * G4 + jg * 4];

        // ---------------- phase 1: HP-slice GEMM into LDS ----------------
        {
            bf16x8 bf[8];
            if (t > 0) {
                #pragma unroll
                for (int ks = 0; ks < 8; ++ks)
                    bf[ks] = *(const bf16x8*)&hr[(((size_t)(b * 4 + mt)) * 8 + ks) * 512 + l * 8];
            }
            bf16x8 bp = *(const bf16x8*)&posAf[(((size_t)(t * BB + b)) * 4 + mt) * 512 + l * 8];
            #pragma unroll
            for (int gg = 0; gg < 2; ++gg) {
                int gtl = gh * 2 + gg;
                int gt = q * 4 + gtl;
                f32x4 a = {0.f, 0.f, 0.f, 0.f};
                if (t > 0) {
                    #pragma unroll
                    for (int ks = 0; ks < 8; ++ks) {
                        bf16x8 af = *(const bf16x8*)&WHf[(((size_t)gt) * 8 + ks) * 512 + l * 8];
                        a = __builtin_amdgcn_mfma_f32_16x16x32_bf16(af, bf[ks], a, 0, 0, 0);
                    }
                }
                bf16x8 ap = *(const bf16x8*)&WposA[(size_t)gt * 512 + l * 8];
                a = __builtin_amdgcn_mfma_f32_16x16x32_bf16(ap, bp, a, 0, 0, 0);
                *(f32x4*)&LDSG[mt * 16 + (l & 15)][gtl * 16 + (l >> 4) * 4] = a;
            }
        }

        // prefetch c gather under MFMA/LDS latency
        float cgv[8] = {0.f, 0.f, 0.f, 0.f, 0.f, 0.f, 0.f, 0.f};
        if (t > 0) {
            const float* cb = cp + (size_t)b * NN * HIDD + jg;
            cgv[0] = cb[(size_t)mi0.x * HIDD];
            cgv[1] = cb[(size_t)mi0.y * HIDD];
            cgv[2] = cb[(size_t)mi0.z * HIDD];
            cgv[3] = cb[(size_t)mi0.w * HIDD];
            cgv[4] = cb[(size_t)mi1.x * HIDD];
            cgv[5] = cb[(size_t)mi1.y * HIDD];
            cgv[6] = cb[(size_t)mi1.z * HIDD];
            cgv[7] = cb[(size_t)mi1.w * HIDD];
        }
        __syncthreads();

        // ---------------- phase 2: cell + max over 8 k's ----------------
        {
            int ms[8] = {mi0.x, mi0.y, mi0.z, mi0.w, mi1.x, mi1.y, mi1.z, mi1.w};
            float hmax = -INFINITY, cmax = -INFINITY;
            #pragma unroll
            for (int kk = 0; kk < 8; ++kk) {
                int m = ms[kk];
                f32x4 g = *(const f32x4*)&LDSG[m][jl * 4];
                float gi = xav.x + g[0];
                float gf = xav.y + g[1];
                float go = xav.z + g[2];
                float gg = xav.w + g[3];
                float ck = fsigm(gf) * cgv[kk] + fsigm(gi) * ftanh(gg);
                float hk = fsigm(go) * ftanh(ck);
                hmax = fmaxf(hmax, hk);
                cmax = fmaxf(cmax, ck);
            }
            if (kh == 1) { cmbH[p] = hmax; cmbC[p] = cmax; }
            __syncthreads();
            if (kh == 0) {
                hmax = fmaxf(hmax, cmbH[p]);
                cmax = fmaxf(cmax, cmbC[p]);
                cn[((size_t)b * NN + n) * HIDD + jg] = cmax;
                out[((size_t)(b * HIDD + jg) * TT + t) * NN + n] = hmax;
                hw[(((size_t)(b * 4 + (n >> 4))) * 8 + (jg >> 5)) * 512 +
                   (((jg >> 3) & 3) * 16 + (n & 15)) * 8 + (jg & 7)] = f2bf(hmax);
            }
        }

        // ---------------- custom grid barrier (1 per step) ----------------
        if (t != TT - 1) {
            __threadfence();                 // release: drain stores, L2 wb
            __syncthreads();
            if (tid == 0) {
                int pos = atomicAdd(&bar[16 + t], 1);       // per-step counter
                if (pos == GRID - 1) {
                    __hip_atomic_store(&bar[0], t + 1, __ATOMIC_RELEASE,
                                       __HIP_MEMORY_SCOPE_AGENT);
                } else {
                    while (__hip_atomic_load(&bar[0], __ATOMIC_RELAXED,
                                             __HIP_MEMORY_SCOPE_AGENT) < t + 1)
                        __builtin_amdgcn_s_sleep(2);
                }
            }
            __syncthreads();
            __threadfence();                 // acquire: invalidate L1/L2
        }
    }
}

// ---------------------------------------------------------------------------
extern "C" void kernel_launch(void* const* d_in, const int* in_sizes, int n_in,
                              void* d_out, int out_size, void* d_ws, size_t ws_size,
                              hipStream_t stream) {
    const float* in   = (const float*)d_in[0];
    const float* W    = (const float*)d_in[2];
    const float* bias = (const float*)d_in[3];
    float* out  = (float*)d_out;
    float* outI = out + (size_t)BB * HIDD * TT * NN;

    float* ws     = (float*)d_ws;
    float* XA     = ws;                                   // 8,388,608 f
    float* biasP  = XA + (size_t)TT * BB * NN * G4;       //     1,024 f
    float* c0     = biasP + G4;                           //    65,536 f
    float* c1     = c0 + (size_t)BB * NN * HIDD;          //    65,536 f
    unsigned short* WXf   = (unsigned short*)(c1 + (size_t)BB * NN * HIDD); // 163,840
    unsigned short* WHf   = WXf + (size_t)64 * 5 * 512;   // 262,144 us
    unsigned short* WposA = WHf + (size_t)64 * 8 * 512;   //  32,768 us
    unsigned short* xf    = WposA + (size_t)64 * 512;     // 1,310,720 us
    unsigned short* hb0   = xf + (size_t)128 * 4 * 5 * 512; // 65,536 us
    unsigned short* hb1   = hb0 + (size_t)BB * NN * HIDD;   // 65,536 us
    unsigned short* posAf = hb1 + (size_t)BB * NN * HIDD;   // 262,144 us
    int* idxw = (int*)(posAf + (size_t)TT * BB * 4 * 512);  // 131,072 i
    int* bar  = idxw + (size_t)TT * BB * NN * KK;           //      64 i

    hipMemsetAsync(bar, 0, sizeof(int) * 64, stream);
    ktrans2<<<64, 256, 0, stream>>>(W, bias, WXf, WHf, WposA, biasP);
    kprep<<<128, 256, 0, stream>>>(in, idxw, outI, xf, posAf);
    kxa3<<<512, 256, 0, stream>>>(xf, WXf, biasP, XA);

    void* args[] = {(void*)&XA, (void*)&WHf, (void*)&WposA, (void*)&posAf,
                    (void*)&hb0, (void*)&hb1, (void*)&idxw,
                    (void*)&c0, (void*)&c1, (void*)&out, (void*)&bar};
    hipLaunchCooperativeKernel((const void*)kloop2, dim3(GRID), dim3(512),
                               args, 0, stream);
}

// Round 9
// 307.956 us; speedup vs baseline: 8.4601x; 8.4601x over previous
//
#include <hip/hip_runtime.h>
#include <math.h>

#define BB 4
#define CC 132
#define TT 32
#define NN 64
#define HIDD 256
#define G4 1024
#define CIN 392
#define KK 16
#define HOFF 136   // CC + OFF: start of h columns in W

typedef __attribute__((ext_vector_type(8))) short bf16x8;
typedef __attribute__((ext_vector_type(4))) float f32x4;

// fast cell math: v_exp_f32 + v_rcp_f32 (1-ulp approx; h-path is bf16-graded)
__device__ __forceinline__ float frcp(float x) { return __builtin_amdgcn_rcpf(x); }
__device__ __forceinline__ float fsigm(float x) { return frcp(1.0f + __expf(-x)); }
__device__ __forceinline__ float ftanh(float x) {
    float e = __expf(2.0f * x);
    return 1.0f - 2.0f * frcp(e + 1.0f);
}
__device__ __forceinline__ unsigned short f2bf(float x) {
    union { float f; unsigned u; } v; v.f = x;
    unsigned r = v.u + 0x7fffu + ((v.u >> 16) & 1u);   // RNE
    return (unsigned short)(r >> 16);
}

// ---------------------------------------------------------------------------
// W -> MFMA fragments, gate-interleaved permutation g' = 4*j + gate.
// grid = 64 (g'-tiles of 16), block = 256.
// ---------------------------------------------------------------------------
__global__ __launch_bounds__(256) void ktrans2(const float* __restrict__ W,
                                               const float* __restrict__ bias,
                                               unsigned short* __restrict__ WXf,
                                               unsigned short* __restrict__ WHf,
                                               unsigned short* __restrict__ WposA,
                                               float* __restrict__ biasP) {
    int gt = blockIdx.x;
    int tid = threadIdx.x;
    __shared__ float Wl[16][CIN];
    for (int row = 0; row < 16; ++row) {
        int orig = (row & 3) * 256 + gt * 4 + (row >> 2);   // gate*256 + j
        for (int c = tid; c < CIN; c += 256)
            Wl[row][c] = W[(size_t)orig * CIN + c];
    }
    __syncthreads();
    for (int f = tid; f < 320; f += 256) {           // WXf: 5 ks x 64 lanes
        int ks = f >> 6, l = f & 63;
        bf16x8 v;
        #pragma unroll
        for (int j = 0; j < 8; ++j) {
            int c = ks * 32 + (l >> 4) * 8 + j;
            float w = (c < CC) ? Wl[l & 15][c] : ((c < HOFF) ? -Wl[l & 15][c] : 0.0f);
            v[j] = (short)f2bf(w);
        }
        *(bf16x8*)&WXf[((size_t)(gt * 5 + ks)) * 512 + l * 8] = v;
    }
    for (int f = tid; f < 512; f += 256) {           // WHf: 8 ks x 64 lanes
        int ks = f >> 6, l = f & 63;
        bf16x8 v;
        #pragma unroll
        for (int j = 0; j < 8; ++j) {
            int c = HOFF + ks * 32 + (l >> 4) * 8 + j;
            v[j] = (short)f2bf(Wl[l & 15][c]);
        }
        *(bf16x8*)&WHf[((size_t)(gt * 8 + ks)) * 512 + l * 8] = v;
    }
    if (tid < 64) {                                  // WposA: 1 ks
        bf16x8 v;
        #pragma unroll
        for (int e = 0; e < 8; ++e) {
            int c = (tid >> 4) * 8 + e;
            v[e] = (c < 4) ? (short)f2bf(Wl[tid & 15][CC + c]) : (short)0;
        }
        *(bf16x8*)&WposA[(size_t)gt * 512 + tid * 8] = v;
    }
    if (tid < 16)
        biasP[gt * 16 + tid] = bias[(tid & 3) * 256 + gt * 4 + (tid >> 2)];
}

// ---------------------------------------------------------------------------
// Fused prep: x -> A-frags; pos -> A-frag k-slice; bit-exact top-k.
// grid = 128 (t,b), block 256.
// ---------------------------------------------------------------------------
__global__ __launch_bounds__(256) void kprep(const float* __restrict__ in,
                                             int* __restrict__ idxw,
                                             float* __restrict__ outI,
                                             unsigned short* __restrict__ xf,
                                             unsigned short* __restrict__ posAf) {
    int t = blockIdx.x >> 2, b = blockIdx.x & 3;
    int tid = threadIdx.x;
    int tprev = t ? t - 1 : 0;

    __shared__ unsigned short X[64][160];
    {
        int n = tid & 63, cg = tid >> 6;
        for (int c = cg; c < 160; c += 4) {
            float v = 0.0f;
            if (c < CC)        v = in[(((size_t)b * CC + c) * TT + t) * NN + n];
            else if (c < HOFF) v = in[(((size_t)b * CC + (c - CC)) * TT + t) * NN + n];
            X[n][c] = f2bf(v);
        }
        __syncthreads();
        for (int i = 0; i < 5; ++i) {
            int f = i * 256 + tid;
            int mtn = f / 320, r = f % 320;
            int ks = r >> 6, l = r & 63;
            uint4 v = *(const uint4*)&X[mtn * 16 + (l & 15)][ks * 32 + (l >> 4) * 8];
            *(uint4*)&xf[(((size_t)(blockIdx.x * 4 + mtn)) * 5 + ks) * 512 + l * 8] = v;
        }
    }
    {
        int mt = tid >> 6, l = tid & 63;
        bf16x8 v;
        #pragma unroll
        for (int e = 0; e < 8; ++e) {
            int c = (l >> 4) * 8 + e;
            float p = (c < 4) ? in[(((size_t)b * CC + c) * TT + tprev) * NN + mt * 16 + (l & 15)] : 0.0f;
            v[e] = (short)f2bf(p);
        }
        *(bf16x8*)&posAf[(((size_t)(t * BB + b)) * 4 + mt) * 512 + l * 8] = v;
    }
    {
        int lane = tid & 63, w = tid >> 6;
        const float* base = in + (size_t)b * CC * TT * NN;
        float p0 = base[(0 * TT + tprev) * NN + lane];
        float p1 = base[(1 * TT + tprev) * NN + lane];
        float p2 = base[(2 * TT + tprev) * NN + lane];
        float q0 = base[(0 * TT + t) * NN + lane];
        float q1 = base[(1 * TT + t) * NN + lane];
        float q2 = base[(2 * TT + t) * NN + lane];
        for (int nn = 0; nn < 16; ++nn) {
            int n = w * 16 + nn;
            float a0 = __shfl(q0, n), a1 = __shfl(q1, n), a2 = __shfl(q2, n);
            float dx = a0 - p0, dy = a1 - p1, dz = a2 - p2;
            float s01 = __fadd_rn(__fmul_rn(dx, dx), __fmul_rn(dy, dy));
            float d = __fadd_rn(s01, __fmul_rn(dz, dz));
            unsigned long long key =
                ((unsigned long long)__float_as_uint(d) << 32) | (unsigned)lane;
            #pragma unroll
            for (int k = 2; k <= 64; k <<= 1) {
                #pragma unroll
                for (int j = k >> 1; j > 0; j >>= 1) {
                    unsigned long long other = __shfl_xor(key, j);
                    bool up = (lane & k) == 0;
                    bool upper = (lane & j) != 0;
                    bool keepMax = up ? upper : !upper;
                    unsigned long long mn = key < other ? key : other;
                    unsigned long long mx = key < other ? other : key;
                    key = keepMax ? mx : mn;
                }
            }
            if (lane < KK) {
                int m = (int)(key & 0xffffffffu);
                idxw[((t * BB + b) * NN + n) * KK + lane] = m;
                outI[((b * TT + t) * NN + n) * KK + lane] = (float)m;
            }
        }
    }
}

// ---------------------------------------------------------------------------
// XA = x*Wx + biasP (MFMA, permuted cols). grid = 512, block = 256 (4 waves).
// ---------------------------------------------------------------------------
__global__ __launch_bounds__(256) void kxa3(const unsigned short* __restrict__ xf,
                                            const unsigned short* __restrict__ WXf,
                                            const float* __restrict__ biasP,
                                            float* __restrict__ XA) {
    int gq = blockIdx.x & 3, tb = blockIdx.x >> 2;
    int w = threadIdx.x >> 6, l = threadIdx.x & 63;
    int gbase = gq * 16 + w * 4;
    f32x4 acc[4][4];
    #pragma unroll
    for (int a = 0; a < 4; ++a)
        #pragma unroll
        for (int g = 0; g < 4; ++g) acc[a][g] = (f32x4){0.f, 0.f, 0.f, 0.f};
    #pragma unroll
    for (int ks = 0; ks < 5; ++ks) {
        bf16x8 af[4], bfr[4];
        #pragma unroll
        for (int m = 0; m < 4; ++m)
            af[m] = *(const bf16x8*)&xf[(((size_t)(tb * 4 + m)) * 5 + ks) * 512 + l * 8];
        #pragma unroll
        for (int g = 0; g < 4; ++g)
            bfr[g] = *(const bf16x8*)&WXf[((size_t)((gbase + g) * 5 + ks)) * 512 + l * 8];
        #pragma unroll
        for (int m = 0; m < 4; ++m)
            #pragma unroll
            for (int g = 0; g < 4; ++g)
                acc[m][g] = __builtin_amdgcn_mfma_f32_16x16x32_bf16(af[m], bfr[g], acc[m][g], 0, 0, 0);
    }
    int rb = tb * 64;
    #pragma unroll
    for (int g = 0; g < 4; ++g) {
        int gcol = (gbase + g) * 16 + (l & 15);
        float bv = biasP[gcol];
        #pragma unroll
        for (int m = 0; m < 4; ++m)
            #pragma unroll
            for (int r = 0; r < 4; ++r) {
                int row = rb + m * 16 + (l >> 4) * 4 + r;
                XA[(size_t)row * G4 + gcol] = acc[m][g][r] + bv;
            }
    }
}

// ---------------------------------------------------------------------------
// Fused per-step kernel. grid = 256: b = bid&3, q = (bid>>2)&15, nh = bid>>6.
// block = 512. Phase 1: HP-slice GEMM -> LDS (2 indep MFMA chains).
// Phase 2: cell with fast rcp transcendentals + max over 8 k's, pair-combine.
// ---------------------------------------------------------------------------
__global__ __launch_bounds__(512) void kstep(const float* __restrict__ XA,
                                             const unsigned short* __restrict__ WHf,
                                             const unsigned short* __restrict__ WposA,
                                             const unsigned short* __restrict__ posAf,
                                             const unsigned short* __restrict__ hr,
                                             unsigned short* __restrict__ hw,
                                             const int* __restrict__ idxw,
                                             const float* __restrict__ cp,
                                             float* __restrict__ cn,
                                             float* __restrict__ out, int t) {
    int bid = blockIdx.x;
    int b = bid & 3, q = (bid >> 2) & 15, nh = bid >> 6;
    int tid = threadIdx.x;
    __shared__ float LDSG[64][68];          // [m][g'local(64)+pad]
    __shared__ float cmbH[256], cmbC[256];

    // phase-2 identities
    int kh = tid >> 8, p = tid & 255;
    int nl = p >> 4, jl = p & 15;
    int n = nh * 16 + nl;
    int jg = q * 16 + jl;

    // earliest loads: this thread's 8 knn indices + its XA quad
    const int* irow = &idxw[((size_t)(t * BB + b) * NN + n) * KK + kh * 8];
    int4 mi0 = *(const int4*)irow;
    int4 mi1 = *(const int4*)(irow + 4);
    const float4 xav = *(const float4*)&XA[((size_t)(t * BB + b) * NN + n) * G4 + jg * 4];

    // ---------------- phase 1: HP-slice GEMM into LDS ----------------
    {
        int wv = tid >> 6, l = tid & 63;
        int mt = wv & 3, gh = wv >> 2;
        bf16x8 bf[8];
        if (t > 0) {
            #pragma unroll
            for (int ks = 0; ks < 8; ++ks)
                bf[ks] = *(const bf16x8*)&hr[(((size_t)(b * 4 + mt)) * 8 + ks) * 512 + l * 8];
        }
        bf16x8 bp = *(const bf16x8*)&posAf[(((size_t)(t * BB + b)) * 4 + mt) * 512 + l * 8];
        #pragma unroll
        for (int gg = 0; gg < 2; ++gg) {
            int gtl = gh * 2 + gg;
            int gt = q * 4 + gtl;
            f32x4 a0 = {0.f, 0.f, 0.f, 0.f};
            f32x4 a1 = {0.f, 0.f, 0.f, 0.f};
            if (t > 0) {
                #pragma unroll
                for (int ks = 0; ks < 8; ks += 2) {    // 2 independent chains
                    bf16x8 af0 = *(const bf16x8*)&WHf[(((size_t)gt) * 8 + ks) * 512 + l * 8];
                    bf16x8 af1 = *(const bf16x8*)&WHf[(((size_t)gt) * 8 + ks + 1) * 512 + l * 8];
                    a0 = __builtin_amdgcn_mfma_f32_16x16x32_bf16(af0, bf[ks], a0, 0, 0, 0);
                    a1 = __builtin_amdgcn_mfma_f32_16x16x32_bf16(af1, bf[ks + 1], a1, 0, 0, 0);
                }
            }
            bf16x8 ap = *(const bf16x8*)&WposA[(size_t)gt * 512 + l * 8];
            a0 = __builtin_amdgcn_mfma_f32_16x16x32_bf16(ap, bp, a0, 0, 0, 0);
            a0[0] += a1[0]; a0[1] += a1[1]; a0[2] += a1[2]; a0[3] += a1[3];
            *(f32x4*)&LDSG[mt * 16 + (l & 15)][gtl * 16 + (l >> 4) * 4] = a0;
        }
    }

    // c gather (depends only on idxw; issued under MFMA/LDS latency)
    float cgv[8] = {0.f, 0.f, 0.f, 0.f, 0.f, 0.f, 0.f, 0.f};
    if (t > 0) {
        const float* cb = cp + (size_t)b * NN * HIDD + jg;
        cgv[0] = cb[(size_t)mi0.x * HIDD];
        cgv[1] = cb[(size_t)mi0.y * HIDD];
        cgv[2] = cb[(size_t)mi0.z * HIDD];
        cgv[3] = cb[(size_t)mi0.w * HIDD];
        cgv[4] = cb[(size_t)mi1.x * HIDD];
        cgv[5] = cb[(size_t)mi1.y * HIDD];
        cgv[6] = cb[(size_t)mi1.z * HIDD];
        cgv[7] = cb[(size_t)mi1.w * HIDD];
    }
    __syncthreads();

    // ---------------- phase 2: cell + max over 8 k's ----------------
    {
        int ms[8] = {mi0.x, mi0.y, mi0.z, mi0.w, mi1.x, mi1.y, mi1.z, mi1.w};
        float hmax = -INFINITY, cmax = -INFINITY;
        #pragma unroll
        for (int kk = 0; kk < 8; ++kk) {
            int m = ms[kk];
            f32x4 g = *(const f32x4*)&LDSG[m][jl * 4];
            float gi = xav.x + g[0];
            float gf = xav.y + g[1];
            float go = xav.z + g[2];
            float gg = xav.w + g[3];
            float ck = fsigm(gf) * cgv[kk] + fsigm(gi) * ftanh(gg);
            float hk = fsigm(go) * ftanh(ck);
            hmax = fmaxf(hmax, hk);
            cmax = fmaxf(cmax, ck);
        }
        if (kh == 1) { cmbH[p] = hmax; cmbC[p] = cmax; }
        __syncthreads();
        if (kh == 0) {
            hmax = fmaxf(hmax, cmbH[p]);
            cmax = fmaxf(cmax, cmbC[p]);
            cn[((size_t)b * NN + n) * HIDD + jg] = cmax;
            out[((size_t)(b * HIDD + jg) * TT + t) * NN + n] = hmax;   // L2-merged
            hw[(((size_t)(b * 4 + (n >> 4))) * 8 + (jg >> 5)) * 512 +
               (((jg >> 3) & 3) * 16 + (n & 15)) * 8 + (jg & 7)] = f2bf(hmax);
        }
    }
}

// ---------------------------------------------------------------------------
extern "C" void kernel_launch(void* const* d_in, const int* in_sizes, int n_in,
                              void* d_out, int out_size, void* d_ws, size_t ws_size,
                              hipStream_t stream) {
    const float* in   = (const float*)d_in[0];
    const float* W    = (const float*)d_in[2];
    const float* bias = (const float*)d_in[3];
    float* out  = (float*)d_out;
    float* outI = out + (size_t)BB * HIDD * TT * NN;

    float* ws     = (float*)d_ws;
    float* XA     = ws;                                   // 8,388,608 f
    float* biasP  = XA + (size_t)TT * BB * NN * G4;       //     1,024 f
    float* c0     = biasP + G4;                           //    65,536 f
    float* c1     = c0 + (size_t)BB * NN * HIDD;          //    65,536 f
    unsigned short* WXf   = (unsigned short*)(c1 + (size_t)BB * NN * HIDD); // 163,840
    unsigned short* WHf   = WXf + (size_t)64 * 5 * 512;   // 262,144 us
    unsigned short* WposA = WHf + (size_t)64 * 8 * 512;   //  32,768 us
    unsigned short* xf    = WposA + (size_t)64 * 512;     // 1,310,720 us
    unsigned short* hb0   = xf + (size_t)128 * 4 * 5 * 512; // 65,536 us
    unsigned short* hb1   = hb0 + (size_t)BB * NN * HIDD;   // 65,536 us
    unsigned short* posAf = hb1 + (size_t)BB * NN * HIDD;   // 262,144 us
    int* idxw = (int*)(posAf + (size_t)TT * BB * 4 * 512);  // 131,072 i

    ktrans2<<<64, 256, 0, stream>>>(W, bias, WXf, WHf, WposA, biasP);
    kprep<<<128, 256, 0, stream>>>(in, idxw, outI, xf, posAf);
    kxa3<<<512, 256, 0, stream>>>(xf, WXf, biasP, XA);

    for (int t = 0; t < TT; ++t) {
        float* cpb = (t & 1) ? c0 : c1;
        float* cnb = (t & 1) ? c1 : c0;
        unsigned short* hrd = (t & 1) ? hb0 : hb1;
        unsigned short* hwr = (t & 1) ? hb1 : hb0;
        kstep<<<256, 512, 0, stream>>>(XA, WHf, WposA, posAf, hrd, hwr,
                                       idxw, cpb, cnb, out, t);
    }
}

// Round 10
// 270.805 us; speedup vs baseline: 9.6207x; 1.1372x over previous
//
#include <hip/hip_runtime.h>
#include <math.h>

#define BB 4
#define CC 132
#define TT 32
#define NN 64
#define HIDD 256
#define G4 1024
#define CIN 392
#define KK 16
#define HOFF 136   // CC + OFF: start of h columns in W

typedef __attribute__((ext_vector_type(8))) short bf16x8;
typedef __attribute__((ext_vector_type(4))) float f32x4;

// fast cell math: v_exp_f32 + v_rcp_f32 (1-ulp approx; h-path is bf16-graded)
__device__ __forceinline__ float frcp(float x) { return __builtin_amdgcn_rcpf(x); }
__device__ __forceinline__ float fsigm(float x) { return frcp(1.0f + __expf(-x)); }
__device__ __forceinline__ float ftanh(float x) {
    float e = __expf(2.0f * x);
    return 1.0f - 2.0f * frcp(e + 1.0f);
}
__device__ __forceinline__ unsigned short f2bf(float x) {
    union { float f; unsigned u; } v; v.f = x;
    unsigned r = v.u + 0x7fffu + ((v.u >> 16) & 1u);   // RNE
    return (unsigned short)(r >> 16);
}

// ---------------------------------------------------------------------------
// ONE setup dispatch, grid = 704, block = 256:
//   bid   0..63 : W -> MFMA fragments (gate-interleaved g' = 4*j + gate)
//   bid  64..191: x -> A-frags (K pad 160) + pos A-frag k-slice   (t,b)
//   bid 192..703: bit-exact top-k, 4 sorts/wave (4x parallelism)  (t,b,quarter)
// ---------------------------------------------------------------------------
__global__ __launch_bounds__(256) void ksetup(const float* __restrict__ in,
                                              const float* __restrict__ W,
                                              const float* __restrict__ bias,
                                              unsigned short* __restrict__ WXf,
                                              unsigned short* __restrict__ WHf,
                                              unsigned short* __restrict__ WposA,
                                              float* __restrict__ biasP,
                                              unsigned short* __restrict__ xf,
                                              unsigned short* __restrict__ posAf,
                                              int* __restrict__ idxw,
                                              float* __restrict__ outI) {
    __shared__ __align__(16) char smem[16 * CIN * 4];   // 25088 B (max of branches)
    int bid = blockIdx.x, tid = threadIdx.x;

    if (bid < 64) {
        // -------- W fragment build --------
        int gt = bid;
        float (*Wl)[CIN] = (float(*)[CIN])smem;
        for (int row = 0; row < 16; ++row) {
            int orig = (row & 3) * 256 + gt * 4 + (row >> 2);   // gate*256 + j
            for (int c = tid; c < CIN; c += 256)
                Wl[row][c] = W[(size_t)orig * CIN + c];
        }
        __syncthreads();
        for (int f = tid; f < 320; f += 256) {           // WXf: 5 ks x 64 lanes
            int ks = f >> 6, l = f & 63;
            bf16x8 v;
            #pragma unroll
            for (int j = 0; j < 8; ++j) {
                int c = ks * 32 + (l >> 4) * 8 + j;
                float w = (c < CC) ? Wl[l & 15][c] : ((c < HOFF) ? -Wl[l & 15][c] : 0.0f);
                v[j] = (short)f2bf(w);
            }
            *(bf16x8*)&WXf[((size_t)(gt * 5 + ks)) * 512 + l * 8] = v;
        }
        for (int f = tid; f < 512; f += 256) {           // WHf: 8 ks x 64 lanes
            int ks = f >> 6, l = f & 63;
            bf16x8 v;
            #pragma unroll
            for (int j = 0; j < 8; ++j) {
                int c = HOFF + ks * 32 + (l >> 4) * 8 + j;
                v[j] = (short)f2bf(Wl[l & 15][c]);
            }
            *(bf16x8*)&WHf[((size_t)(gt * 8 + ks)) * 512 + l * 8] = v;
        }
        if (tid < 64) {                                  // WposA: 1 ks
            bf16x8 v;
            #pragma unroll
            for (int e = 0; e < 8; ++e) {
                int c = (tid >> 4) * 8 + e;
                v[e] = (c < 4) ? (short)f2bf(Wl[tid & 15][CC + c]) : (short)0;
            }
            *(bf16x8*)&WposA[(size_t)gt * 512 + tid * 8] = v;
        }
        if (tid < 16)
            biasP[gt * 16 + tid] = bias[(tid & 3) * 256 + gt * 4 + (tid >> 2)];
    } else if (bid < 192) {
        // -------- x / pos fragment build --------
        int tb = bid - 64;
        int t = tb >> 2, b = tb & 3;
        int tprev = t ? t - 1 : 0;
        unsigned short (*X)[168] = (unsigned short(*)[168])smem;  // 336B rows, 16B-aligned
        {
            int n = tid & 63, cg = tid >> 6;
            #pragma unroll
            for (int i = 0; i < 10; ++i) {
                int c = cg * 4 + i * 16;                 // multiple of 4; no 132-straddle
                short4 s;
                #pragma unroll
                for (int j = 0; j < 4; ++j) {
                    int cc = c + j;
                    float v = 0.0f;
                    if (cc < CC)        v = in[(((size_t)b * CC + cc) * TT + t) * NN + n];
                    else if (cc < HOFF) v = in[(((size_t)b * CC + (cc - CC)) * TT + t) * NN + n];
                    ((unsigned short*)&s)[j] = f2bf(v);
                }
                *(short4*)&X[n][c] = s;
            }
            __syncthreads();
            for (int i = 0; i < 5; ++i) {          // 4 mtn x 5 ks x 64 l = 1280 frags
                int f = i * 256 + tid;
                int mtn = f / 320, r = f % 320;
                int ks = r >> 6, l = r & 63;
                uint4 v = *(const uint4*)&X[mtn * 16 + (l & 15)][ks * 32 + (l >> 4) * 8];
                *(uint4*)&xf[(((size_t)(tb * 4 + mtn)) * 5 + ks) * 512 + l * 8] = v;
            }
        }
        {
            int mt = tid >> 6, l = tid & 63;
            bf16x8 v;
            #pragma unroll
            for (int e = 0; e < 8; ++e) {
                int c = (l >> 4) * 8 + e;
                float p = (c < 4) ? in[(((size_t)b * CC + c) * TT + tprev) * NN + mt * 16 + (l & 15)] : 0.0f;
                v[e] = (short)f2bf(p);
            }
            *(bf16x8*)&posAf[(((size_t)(t * BB + b)) * 4 + mt) * 512 + l * 8] = v;
        }
    } else {
        // -------- top-k (bit-exact; 1 wave = 4 sorts) --------
        int idx2 = bid - 192;
        int tb = idx2 >> 2, qr = idx2 & 3;
        int t = tb >> 2, b = tb & 3, tprev = t ? t - 1 : 0;
        int lane = tid & 63, w = tid >> 6;
        const float* base = in + (size_t)b * CC * TT * NN;
        float p0 = base[(0 * TT + tprev) * NN + lane];
        float p1 = base[(1 * TT + tprev) * NN + lane];
        float p2 = base[(2 * TT + tprev) * NN + lane];
        float q0 = base[(0 * TT + t) * NN + lane];
        float q1 = base[(1 * TT + t) * NN + lane];
        float q2 = base[(2 * TT + t) * NN + lane];
        for (int nn = 0; nn < 4; ++nn) {
            int n = qr * 16 + w * 4 + nn;
            float a0 = __shfl(q0, n), a1 = __shfl(q1, n), a2 = __shfl(q2, n);
            float dx = a0 - p0, dy = a1 - p1, dz = a2 - p2;
            float s01 = __fadd_rn(__fmul_rn(dx, dx), __fmul_rn(dy, dy));
            float d = __fadd_rn(s01, __fmul_rn(dz, dz));
            unsigned long long key =
                ((unsigned long long)__float_as_uint(d) << 32) | (unsigned)lane;
            #pragma unroll
            for (int k = 2; k <= 64; k <<= 1) {
                #pragma unroll
                for (int j = k >> 1; j > 0; j >>= 1) {
                    unsigned long long other = __shfl_xor(key, j);
                    bool up = (lane & k) == 0;
                    bool upper = (lane & j) != 0;
                    bool keepMax = up ? upper : !upper;
                    unsigned long long mn = key < other ? key : other;
                    unsigned long long mx = key < other ? other : key;
                    key = keepMax ? mx : mn;
                }
            }
            if (lane < KK) {
                int m = (int)(key & 0xffffffffu);
                idxw[((t * BB + b) * NN + n) * KK + lane] = m;
                outI[((b * TT + t) * NN + n) * KK + lane] = (float)m;
            }
        }
    }
}

// ---------------------------------------------------------------------------
// Fused per-step kernel. grid = 256: b = bid&3, q = (bid>>2)&15, nh = bid>>6.
// block = 512 (8 waves).
// Phase 1: HP-slice GEMM -> LDSG  (all waves, 2 indep MFMA chains)
//          + XA-slice GEMM -> XAL (waves gh==1, operand-swapped, + bias)
// Phase 2: cell with rcp transcendentals + max over 8 k's, pair-combine.
// ---------------------------------------------------------------------------
__global__ __launch_bounds__(512) void kstep(const unsigned short* __restrict__ WHf,
                                             const unsigned short* __restrict__ WposA,
                                             const unsigned short* __restrict__ WXf,
                                             const unsigned short* __restrict__ xf,
                                             const unsigned short* __restrict__ posAf,
                                             const float* __restrict__ biasP,
                                             const unsigned short* __restrict__ hr,
                                             unsigned short* __restrict__ hw,
                                             const int* __restrict__ idxw,
                                             const float* __restrict__ cp,
                                             float* __restrict__ cn,
                                             float* __restrict__ out, int t) {
    int bid = blockIdx.x;
    int b = bid & 3, q = (bid >> 2) & 15, nh = bid >> 6;
    int tid = threadIdx.x;
    __shared__ float LDSG[64][68];          // HP[m][g'local(64)+pad]
    __shared__ float XAL[16][68];           // XA[n_local][g'local(64)+pad]
    __shared__ float cmbH[256], cmbC[256];

    // phase-2 identities
    int kh = tid >> 8, p = tid & 255;
    int nl = p >> 4, jl = p & 15;
    int n = nh * 16 + nl;
    int jg = q * 16 + jl;

    // earliest loads: this thread's 8 knn indices
    const int* irow = &idxw[((size_t)(t * BB + b) * NN + n) * KK + kh * 8];
    int4 mi0 = *(const int4*)irow;
    int4 mi1 = *(const int4*)(irow + 4);

    // ---------------- phase 1 ----------------
    {
        int wv = tid >> 6, l = tid & 63;
        int mt = wv & 3, gh = wv >> 2;
        bf16x8 bf[8];
        if (t > 0) {
            #pragma unroll
            for (int ks = 0; ks < 8; ++ks)
                bf[ks] = *(const bf16x8*)&hr[(((size_t)(b * 4 + mt)) * 8 + ks) * 512 + l * 8];
        }
        bf16x8 bp = *(const bf16x8*)&posAf[(((size_t)(t * BB + b)) * 4 + mt) * 512 + l * 8];
        #pragma unroll
        for (int gg = 0; gg < 2; ++gg) {
            int gtl = gh * 2 + gg;
            int gt = q * 4 + gtl;
            f32x4 a0 = {0.f, 0.f, 0.f, 0.f};
            f32x4 a1 = {0.f, 0.f, 0.f, 0.f};
            if (t > 0) {
                #pragma unroll
                for (int ks = 0; ks < 8; ks += 2) {    // 2 independent chains
                    bf16x8 af0 = *(const bf16x8*)&WHf[(((size_t)gt) * 8 + ks) * 512 + l * 8];
                    bf16x8 af1 = *(const bf16x8*)&WHf[(((size_t)gt) * 8 + ks + 1) * 512 + l * 8];
                    a0 = __builtin_amdgcn_mfma_f32_16x16x32_bf16(af0, bf[ks], a0, 0, 0, 0);
                    a1 = __builtin_amdgcn_mfma_f32_16x16x32_bf16(af1, bf[ks + 1], a1, 0, 0, 0);
                }
            }
            bf16x8 ap = *(const bf16x8*)&WposA[(size_t)gt * 512 + l * 8];
            a0 = __builtin_amdgcn_mfma_f32_16x16x32_bf16(ap, bp, a0, 0, 0, 0);
            a0[0] += a1[0]; a0[1] += a1[1]; a0[2] += a1[2]; a0[3] += a1[3];
            *(f32x4*)&LDSG[mt * 16 + (l & 15)][gtl * 16 + (l >> 4) * 4] = a0;
        }
        // XA slice: waves gh==1, gtl = mt.  D[g'][n] = W_x · x  (+ bias)
        if (gh == 1) {
            int gtl = mt, gt = q * 4 + gtl;
            f32x4 a = {0.f, 0.f, 0.f, 0.f};
            #pragma unroll
            for (int ks = 0; ks < 5; ++ks) {
                bf16x8 aw = *(const bf16x8*)&WXf[((size_t)(gt * 5 + ks)) * 512 + l * 8];
                bf16x8 bx = *(const bf16x8*)&xf[((((size_t)(t * BB + b)) * 4 + nh) * 5 + ks) * 512 + l * 8];
                a = __builtin_amdgcn_mfma_f32_16x16x32_bf16(aw, bx, a, 0, 0, 0);
            }
            f32x4 bv = *(const f32x4*)&biasP[gt * 16 + (l >> 4) * 4];
            a[0] += bv[0]; a[1] += bv[1]; a[2] += bv[2]; a[3] += bv[3];
            *(f32x4*)&XAL[l & 15][gtl * 16 + (l >> 4) * 4] = a;
        }
    }

    // c gather (depends only on idxw; issued under MFMA/LDS latency)
    float cgv[8] = {0.f, 0.f, 0.f, 0.f, 0.f, 0.f, 0.f, 0.f};
    if (t > 0) {
        const float* cb = cp + (size_t)b * NN * HIDD + jg;
        cgv[0] = cb[(size_t)mi0.x * HIDD];
        cgv[1] = cb[(size_t)mi0.y * HIDD];
        cgv[2] = cb[(size_t)mi0.z * HIDD];
        cgv[3] = cb[(size_t)mi0.w * HIDD];
        cgv[4] = cb[(size_t)mi1.x * HIDD];
        cgv[5] = cb[(size_t)mi1.y * HIDD];
        cgv[6] = cb[(size_t)mi1.z * HIDD];
        cgv[7] = cb[(size_t)mi1.w * HIDD];
    }
    __syncthreads();

    // ---------------- phase 2: cell + max over 8 k's ----------------
    {
        const f32x4 xav = *(const f32x4*)&XAL[nl][jl * 4];
        int ms[8] = {mi0.x, mi0.y, mi0.z, mi0.w, mi1.x, mi1.y, mi1.z, mi1.w};
        float hmax = -INFINITY, cmax = -INFINITY;
        #pragma unroll
        for (int kk = 0; kk < 8; ++kk) {
            int m = ms[kk];
            f32x4 g = *(const f32x4*)&LDSG[m][jl * 4];
            float gi = xav[0] + g[0];
            float gf = xav[1] + g[1];
            float go = xav[2] + g[2];
            float gg = xav[3] + g[3];
            float ck = fsigm(gf) * cgv[kk] + fsigm(gi) * ftanh(gg);
            float hk = fsigm(go) * ftanh(ck);
            hmax = fmaxf(hmax, hk);
            cmax = fmaxf(cmax, ck);
        }
        if (kh == 1) { cmbH[p] = hmax; cmbC[p] = cmax; }
        __syncthreads();
        if (kh == 0) {
            hmax = fmaxf(hmax, cmbH[p]);
            cmax = fmaxf(cmax, cmbC[p]);
            cn[((size_t)b * NN + n) * HIDD + jg] = cmax;
            out[((size_t)(b * HIDD + jg) * TT + t) * NN + n] = hmax;   // L2-merged
            hw[(((size_t)(b * 4 + (n >> 4))) * 8 + (jg >> 5)) * 512 +
               (((jg >> 3) & 3) * 16 + (n & 15)) * 8 + (jg & 7)] = f2bf(hmax);
        }
    }
}

// ---------------------------------------------------------------------------
extern "C" void kernel_launch(void* const* d_in, const int* in_sizes, int n_in,
                              void* d_out, int out_size, void* d_ws, size_t ws_size,
                              hipStream_t stream) {
    const float* in   = (const float*)d_in[0];
    const float* W    = (const float*)d_in[2];
    const float* bias = (const float*)d_in[3];
    float* out  = (float*)d_out;
    float* outI = out + (size_t)BB * HIDD * TT * NN;

    float* ws     = (float*)d_ws;
    float* biasP  = ws;                                   //     1,024 f
    float* c0     = biasP + G4;                           //    65,536 f
    float* c1     = c0 + (size_t)BB * NN * HIDD;          //    65,536 f
    unsigned short* WXf   = (unsigned short*)(c1 + (size_t)BB * NN * HIDD); // 163,840
    unsigned short* WHf   = WXf + (size_t)64 * 5 * 512;   // 262,144 us
    unsigned short* WposA = WHf + (size_t)64 * 8 * 512;   //  32,768 us
    unsigned short* xf    = WposA + (size_t)64 * 512;     // 1,310,720 us
    unsigned short* hb0   = xf + (size_t)128 * 4 * 5 * 512; // 65,536 us
    unsigned short* hb1   = hb0 + (size_t)BB * NN * HIDD;   // 65,536 us
    unsigned short* posAf = hb1 + (size_t)BB * NN * HIDD;   // 262,144 us
    int* idxw = (int*)(posAf + (size_t)TT * BB * 4 * 512);  // 131,072 i

    ksetup<<<704, 256, 0, stream>>>(in, W, bias, WXf, WHf, WposA, biasP,
                                    xf, posAf, idxw, outI);

    for (int t = 0; t < TT; ++t) {
        float* cpb = (t & 1) ? c0 : c1;
        float* cnb = (t & 1) ? c1 : c0;
        unsigned short* hrd = (t & 1) ? hb0 : hb1;
        unsigned short* hwr = (t & 1) ? hb1 : hb0;
        kstep<<<256, 512, 0, stream>>>(WHf, WposA, WXf, xf, posAf, biasP,
                                       hrd, hwr, idxw, cpb, cnb, out, t);
    }
}